// Round 8
// baseline (207.297 us; speedup 1.0000x reference)
//
#include <hip/hip_runtime.h>

#define N_NODES 50000
#define N_EDGES 800000
#define SCAN_BLOCKS ((N_NODES + 255) / 256)   // 196
#define CHUNKS 64
#define EDGES_PER_CHUNK (N_EDGES / CHUNKS)    // 12500
#define HALF_NODES 25000
#define WORDS_PER_HALF 12500                  // u32 words (2 packed u16 counts each)
#define REP_WORDS 25000                       // u32 words per (arr,chunk) replica
#define HALF_SRC 25000                        // src-split gather phase size
// IN=64, HID=128, OUT=64

typedef unsigned short ushort_t;
typedef __attribute__((ext_vector_type(8))) short bf16x8;   // 8 bf16 (4 VGPRs)
typedef __attribute__((ext_vector_type(4))) float f32x4;

static __device__ __forceinline__ ushort_t f2bf(float f) {
    unsigned u = __float_as_uint(f);
    unsigned r = (u + 0x7fffu + ((u >> 16) & 1u)) >> 16;   // RNE
    return (ushort_t)r;
}
static __device__ __forceinline__ float bf2f(ushort_t u) {
    return __uint_as_float(((unsigned)u) << 16);
}

// Per-chunk privatized histogram: block (arr, half, chunk) counts its 12500
// edges' ids falling in its node-half into packed-u16 LDS counters, then
// writes the 50KB replica non-atomically. No global atomics.
__global__ __launch_bounds__(256) void hist_kernel(const int* __restrict__ src,
                                                   const int* __restrict__ dst,
                                                   unsigned int* __restrict__ rep) {
    __shared__ unsigned int cnt[WORDS_PER_HALF];
    int bid = blockIdx.x;
    int chunk = bid & 63;
    int hf = (bid >> 6) & 1;
    int arr = bid >> 7;
    const int* ids = arr ? dst : src;
    int tid = threadIdx.x;
    for (int i = tid; i < WORDS_PER_HALF; i += 256) cnt[i] = 0;
    __syncthreads();
    int base = hf * HALF_NODES;
    int ebeg = chunk * EDGES_PER_CHUNK;
    for (int i = tid; i < EDGES_PER_CHUNK; i += 256) {
        int v = __builtin_nontemporal_load(&ids[ebeg + i]) - base;
        if ((unsigned)v < (unsigned)HALF_NODES)
            atomicAdd(&cnt[v >> 1], 1u << ((v & 1) << 4));  // LDS atomic, packed u16
    }
    __syncthreads();
    unsigned int* o = rep + ((size_t)arr * CHUNKS + chunk) * REP_WORDS + hf * WORDS_PER_HALF;
    for (int i = tid; i < WORDS_PER_HALF; i += 256) o[i] = cnt[i];
}

// scanA: one pass over dst replicas yields BOTH indeg and u16 local per-chunk
// prefixes (cbase16); src replicas -> norm_src; fused xs prescale; block scan.
// Assumes in-degree <= 65535 (holds for E=800k random; max ~45).
__global__ __launch_bounds__(256) void scanA_kernel(
        const unsigned int* __restrict__ rep, const float* __restrict__ x,
        int* __restrict__ indeg, int* __restrict__ tmp_incl, int* __restrict__ bsum,
        float* __restrict__ norm_src, float* __restrict__ norm_dst,
        ushort_t* __restrict__ cbase16, ushort_t* __restrict__ xs) {
    __shared__ int lds[256];
    int tid = threadIdx.x;
    int i = blockIdx.x * 256 + tid;
    int id = 0;
    if (i < N_NODES) {
        int w = i >> 1, sh = (i & 1) << 4;
        const unsigned int* repd = rep + (size_t)CHUNKS * REP_WORDS;  // arr=1 (dst)
        int running = 0;
        #pragma unroll 8
        for (int c = 0; c < CHUNKS; c++) {
            cbase16[(size_t)c * N_NODES + i] = (ushort_t)running;     // local prefix
            running += (int)((repd[(size_t)c * REP_WORDS + w] >> sh) & 0xffffu);
        }
        id = running;
        indeg[i] = id;
        norm_dst[i] = 1.0f / sqrtf((float)max(id, 1));
        int od = 0;
        #pragma unroll 8
        for (int c = 0; c < CHUNKS; c++)
            od += (int)((rep[(size_t)c * REP_WORDS + w] >> sh) & 0xffffu);  // arr=0 (src)
        float ns = 1.0f / sqrtf((float)max(od, 1));
        norm_src[i] = ns;
        // fused prescale: xs row i = bf16(x row * ns)
        #pragma unroll
        for (int q = 0; q < 16; q++) {
            float4 v = *(const float4*)&x[(size_t)i * 64 + q * 4];
            ushort_t* o = &xs[(size_t)i * 64 + q * 4];
            o[0] = f2bf(v.x * ns); o[1] = f2bf(v.y * ns);
            o[2] = f2bf(v.z * ns); o[3] = f2bf(v.w * ns);
        }
    }
    lds[tid] = id;
    __syncthreads();
    for (int off = 1; off < 256; off <<= 1) {
        int t = (tid >= off) ? lds[tid - off] : 0;
        __syncthreads();
        lds[tid] += t;
        __syncthreads();
    }
    if (i < N_NODES) tmp_incl[i] = lds[tid];
    if (tid == 255) bsum[blockIdx.x] = lds[255];
}

// scan2: exclusive scan of block sums (1 block). Also writes row_start[N].
__global__ __launch_bounds__(256) void scan2_kernel(const int* __restrict__ bsum,
                                                    int* __restrict__ bofs,
                                                    int* __restrict__ row_start) {
    __shared__ int lds[256];
    int tid = threadIdx.x;
    lds[tid] = (tid < SCAN_BLOCKS) ? bsum[tid] : 0;
    __syncthreads();
    for (int off = 1; off < 256; off <<= 1) {
        int t = (tid >= off) ? lds[tid - off] : 0;
        __syncthreads();
        lds[tid] += t;
        __syncthreads();
    }
    if (tid < SCAN_BLOCKS) bofs[tid] = (tid == 0) ? 0 : lds[tid - 1];
    if (tid == SCAN_BLOCKS - 1) row_start[N_NODES] = lds[tid];
}

// scanB: row_start finalize only.
__global__ __launch_bounds__(256) void scanB_kernel(const int* __restrict__ indeg,
                                                    const int* __restrict__ tmp_incl,
                                                    const int* __restrict__ bofs,
                                                    int* __restrict__ row_start) {
    int i = blockIdx.x * 256 + threadIdx.x;
    if (i < N_NODES) row_start[i] = bofs[blockIdx.x] + tmp_incl[i] - indeg[i];
}

// Counting-sort CSR fill: pos = row_start[d] + cbase16[chunk][d] + LDS rank.
__global__ __launch_bounds__(256) void fill2_kernel(const int* __restrict__ src,
                                                    const int* __restrict__ dst,
                                                    const int* __restrict__ row_start,
                                                    const ushort_t* __restrict__ cbase16,
                                                    int* __restrict__ edge_src) {
    __shared__ unsigned int rank[WORDS_PER_HALF];
    int chunk = blockIdx.x & 63;
    int hf = blockIdx.x >> 6;
    int tid = threadIdx.x;
    for (int i = tid; i < WORDS_PER_HALF; i += 256) rank[i] = 0;
    __syncthreads();
    int base = hf * HALF_NODES;
    int ebeg = chunk * EDGES_PER_CHUNK;
    for (int i = tid; i < EDGES_PER_CHUNK; i += 256) {
        int d = __builtin_nontemporal_load(&dst[ebeg + i]);
        int v = d - base;
        if ((unsigned)v < (unsigned)HALF_NODES) {
            int sh = (v & 1) << 4;
            unsigned old = atomicAdd(&rank[v >> 1], 1u << sh);
            int r = (int)((old >> sh) & 0xffffu);
            int pos = row_start[d] + (int)cbase16[(size_t)chunk * N_NODES + d] + r;
            edge_src[pos] = __builtin_nontemporal_load(&src[ebeg + i]);
        }
    }
}

// Src-split quad-row gather, PASS selects src range [PASS*25000, +25000):
// the per-pass feature working set (3.2MB bf16) is L2-resident per XCD.
// Out-of-range edges clamp load to range base (hot line) and multiply by 0.
// PASS 1 adds PASS 0's partial (launch boundary guarantees completion).
template <int PASS>
__global__ __launch_bounds__(256) void gather1_kernel(
        const ushort_t* __restrict__ xs, const int* __restrict__ edge_src,
        const int* __restrict__ row_start, float* __restrict__ agg) {
    const int lo = PASS * HALF_SRC, hi = lo + HALF_SRC;
    int node = (blockIdx.x * blockDim.x + threadIdx.x) >> 6;
    int lane = threadIdx.x & 63;
    int grp = lane >> 4;
    int lpos = lane & 15;
    int beg = row_start[node];
    int end = row_start[node + 1];
    float a0 = 0.f, a1 = 0.f, a2 = 0.f, a3 = 0.f;
    for (int i = beg; i < end; i += 64) {
        int cnt = min(end - i, 64);
        int ids = (lane < cnt) ? __builtin_nontemporal_load(&edge_src[i + lane]) : 0;
        for (int t = 0; t < cnt; t += 16) {
            #pragma unroll
            for (int q = 0; q < 4; q++) {
                int j = t + 4 * q + grp;
                int jj = max(min(j, cnt - 1), 0);
                int s = __builtin_amdgcn_ds_bpermute(jj << 2, ids);
                bool ok = (j < cnt) && (s >= lo) && (s < hi);
                int sc = ok ? s : lo;
                uint2 v = *(const uint2*)&xs[(size_t)sc * 64 + lpos * 4];
                float m = ok ? 1.f : 0.f;
                a0 = fmaf(__uint_as_float(v.x << 16), m, a0);
                a1 = fmaf(__uint_as_float(v.x & 0xffff0000u), m, a1);
                a2 = fmaf(__uint_as_float(v.y << 16), m, a2);
                a3 = fmaf(__uint_as_float(v.y & 0xffff0000u), m, a3);
            }
        }
    }
    a0 += __shfl_xor(a0, 16, 64); a1 += __shfl_xor(a1, 16, 64);
    a2 += __shfl_xor(a2, 16, 64); a3 += __shfl_xor(a3, 16, 64);
    a0 += __shfl_xor(a0, 32, 64); a1 += __shfl_xor(a1, 32, 64);
    a2 += __shfl_xor(a2, 32, 64); a3 += __shfl_xor(a3, 32, 64);
    if (grp == 0) {
        float4 res = make_float4(a0, a1, a2, a3);
        float4* o = (float4*)&agg[(size_t)node * 64 + lpos * 4];
        if (PASS == 1) {
            float4 p = *o;
            res.x += p.x; res.y += p.y; res.z += p.z; res.w += p.w;
        }
        *o = res;
    }
}

template <int PASS>
__global__ __launch_bounds__(256) void gather2_kernel(
        const ushort_t* __restrict__ h2, const int* __restrict__ edge_src,
        const int* __restrict__ row_start, const float* __restrict__ norm_dst,
        const float* __restrict__ b2, float* __restrict__ out) {
    const int lo = PASS * HALF_SRC, hi = lo + HALF_SRC;
    int node = (blockIdx.x * blockDim.x + threadIdx.x) >> 6;
    int lane = threadIdx.x & 63;
    int grp = lane >> 4;
    int lpos = lane & 15;
    int beg = row_start[node];
    int end = row_start[node + 1];
    float a0 = 0.f, a1 = 0.f, a2 = 0.f, a3 = 0.f;
    for (int i = beg; i < end; i += 64) {
        int cnt = min(end - i, 64);
        int ids = (lane < cnt) ? __builtin_nontemporal_load(&edge_src[i + lane]) : 0;
        for (int t = 0; t < cnt; t += 16) {
            #pragma unroll
            for (int q = 0; q < 4; q++) {
                int j = t + 4 * q + grp;
                int jj = max(min(j, cnt - 1), 0);
                int s = __builtin_amdgcn_ds_bpermute(jj << 2, ids);
                bool ok = (j < cnt) && (s >= lo) && (s < hi);
                int sc = ok ? s : lo;
                uint2 v = *(const uint2*)&h2[(size_t)sc * 64 + lpos * 4];
                float m = ok ? 1.f : 0.f;
                a0 = fmaf(__uint_as_float(v.x << 16), m, a0);
                a1 = fmaf(__uint_as_float(v.x & 0xffff0000u), m, a1);
                a2 = fmaf(__uint_as_float(v.y << 16), m, a2);
                a3 = fmaf(__uint_as_float(v.y & 0xffff0000u), m, a3);
            }
        }
    }
    a0 += __shfl_xor(a0, 16, 64); a1 += __shfl_xor(a1, 16, 64);
    a2 += __shfl_xor(a2, 16, 64); a3 += __shfl_xor(a3, 16, 64);
    a0 += __shfl_xor(a0, 32, 64); a1 += __shfl_xor(a1, 32, 64);
    a2 += __shfl_xor(a2, 32, 64); a3 += __shfl_xor(a3, 32, 64);
    if (grp == 0) {
        float4* o = (float4*)&out[(size_t)node * 64 + lpos * 4];
        if (PASS == 0) {
            *o = make_float4(a0, a1, a2, a3);       // raw partial
        } else {
            float4 p = *o;
            float nd = norm_dst[node];
            float4 bb = *(const float4*)&b2[lpos * 4];
            *o = make_float4((p.x + a0) * nd + bb.x, (p.y + a1) * nd + bb.y,
                             (p.z + a2) * nd + bb.z, (p.w + a3) * nd + bb.w);
        }
    }
}

// MFMA fused MLP. Per block: 64 rows, 4 waves, each wave owns 16 rows.
// Layer1: [64x64]@[64x128] via hi/lo-split bf16 A (fp32-grade A). Layer2:
// [64x128]@[128x64] single bf16. Row padding (72/136 u16) spreads LDS banks.
__global__ __launch_bounds__(256) void gemm_fused_kernel(
        const float* __restrict__ agg, const float* __restrict__ W1,
        const float* __restrict__ b1, const float* __restrict__ W2,
        const float* __restrict__ norm_dst, const float* __restrict__ norm_src,
        ushort_t* __restrict__ h2) {
    __shared__ ushort_t mem[18432];   // 36 KB
    ushort_t* As_hi = mem;            // [64][72]
    ushort_t* As_lo = mem + 4608;     // [64][72]
    ushort_t* Wt1   = mem + 9216;     // [128 n][72 k]
    int tid = threadIdx.x;
    int rowbase = blockIdx.x * 64;

    for (int i = tid; i < 8192; i += 256) {
        int k = i >> 7, n = i & 127;
        Wt1[n * 72 + k] = f2bf(W1[i]);
    }
    for (int i = tid; i < 1024; i += 256) {
        int row = i >> 4;
        int c = (i & 15) * 4;
        int gr = rowbase + row;
        float4 v = make_float4(0.f, 0.f, 0.f, 0.f);
        if (gr < N_NODES) v = *(const float4*)&agg[(size_t)gr * 64 + c];
        float va[4] = {v.x, v.y, v.z, v.w};
        int base = row * 72 + c;
        #pragma unroll
        for (int q = 0; q < 4; q++) {
            ushort_t h = f2bf(va[q]);
            As_hi[base + q] = h;
            As_lo[base + q] = f2bf(va[q] - bf2f(h));
        }
    }
    __syncthreads();

    int lane = tid & 63;
    int w = tid >> 6;          // wave id 0..3 -> rows 16w..16w+15
    int lr = lane & 15;        // A-row / B-col within tile
    int hi8 = lane >> 4;       // k-group 0..3
    int a_off = (16 * w + lr) * 72 + hi8 * 8;

    f32x4 acc[8] = {};
    #pragma unroll
    for (int ks = 0; ks < 2; ks++) {
        bf16x8 ah = *(bf16x8*)&As_hi[a_off + ks * 32];
        bf16x8 al = *(bf16x8*)&As_lo[a_off + ks * 32];
        #pragma unroll
        for (int ct = 0; ct < 8; ct++) {
            bf16x8 b = *(bf16x8*)&Wt1[(ct * 16 + lr) * 72 + ks * 32 + hi8 * 8];
            acc[ct] = __builtin_amdgcn_mfma_f32_16x16x32_bf16(ah, b, acc[ct], 0, 0, 0);
            acc[ct] = __builtin_amdgcn_mfma_f32_16x16x32_bf16(al, b, acc[ct], 0, 0, 0);
        }
    }

    int row4 = hi8 * 4;
    float nd[4], ns[4];
    #pragma unroll
    for (int r = 0; r < 4; r++) {
        int gr = rowbase + 16 * w + row4 + r;
        nd[r] = (gr < N_NODES) ? norm_dst[gr] : 0.f;
        ns[r] = (gr < N_NODES) ? norm_src[gr] : 0.f;
    }
    __syncthreads();

    ushort_t* Hs  = mem;          // [64][136]
    ushort_t* Wt2 = mem + 8704;   // [64 n][136 k]
    for (int i = tid; i < 8192; i += 256) {
        int k = i >> 6, n = i & 63;
        Wt2[n * 136 + k] = f2bf(W2[i]);
    }
    #pragma unroll
    for (int ct = 0; ct < 8; ct++) {
        float bb = b1[ct * 16 + lr];
        #pragma unroll
        for (int r = 0; r < 4; r++) {
            float v = fmaxf(acc[ct][r] * nd[r] + bb, 0.f) * ns[r];
            Hs[(16 * w + row4 + r) * 136 + ct * 16 + lr] = f2bf(v);
        }
    }
    __syncthreads();

    f32x4 acc2[4] = {};
    int a2_off = (16 * w + lr) * 136 + hi8 * 8;
    #pragma unroll
    for (int ks = 0; ks < 4; ks++) {
        bf16x8 a2 = *(bf16x8*)&Hs[a2_off + ks * 32];
        #pragma unroll
        for (int ct = 0; ct < 4; ct++) {
            bf16x8 b = *(bf16x8*)&Wt2[(ct * 16 + lr) * 136 + ks * 32 + hi8 * 8];
            acc2[ct] = __builtin_amdgcn_mfma_f32_16x16x32_bf16(a2, b, acc2[ct], 0, 0, 0);
        }
    }
    #pragma unroll
    for (int ct = 0; ct < 4; ct++) {
        #pragma unroll
        for (int r = 0; r < 4; r++) {
            int gr = rowbase + 16 * w + row4 + r;
            if (gr < N_NODES)
                h2[(size_t)gr * 64 + ct * 16 + lr] = f2bf(acc2[ct][r]);
        }
    }
}

extern "C" void kernel_launch(void* const* d_in, const int* in_sizes, int n_in,
                              void* d_out, int out_size, void* d_ws, size_t ws_size,
                              hipStream_t stream) {
    const float* x  = (const float*)d_in[0];
    const float* W1 = (const float*)d_in[1];
    const float* b1 = (const float*)d_in[2];
    const float* W2 = (const float*)d_in[3];
    const float* b2 = (const float*)d_in[4];
    const int* src  = (const int*)d_in[5];
    const int* dst  = (const int*)d_in[6];
    float* out = (float*)d_out;

    int* indeg = (int*)d_ws;                        // N
    float* norm_src = (float*)(indeg + N_NODES);    // N
    float* norm_dst = norm_src + N_NODES;           // N
    int* row_start = (int*)(norm_dst + N_NODES);    // N+1
    int* tmp_incl = row_start + N_NODES + 1;        // N
    int* bsum = tmp_incl + N_NODES;                 // SCAN_BLOCKS
    int* bofs = bsum + SCAN_BLOCKS;                 // SCAN_BLOCKS
    unsigned int* rep = (unsigned int*)(bofs + SCAN_BLOCKS);      // 2*64*25000 u32
    int* edge_src = (int*)(rep + (size_t)2 * CHUNKS * REP_WORDS); // E
    float* agg1 = (float*)(edge_src + N_EDGES);     // N*64 f32
    ushort_t* cbase16 = (ushort_t*)agg1;            // 64*N u16, aliases agg1 (dead after fill2)
    ushort_t* xs = (ushort_t*)(agg1 + (size_t)N_NODES * 64);  // N*64 bf16
    ushort_t* h2 = xs + (size_t)N_NODES * 64;                 // N*64 bf16

    hist_kernel<<<256, 256, 0, stream>>>(src, dst, rep);
    scanA_kernel<<<SCAN_BLOCKS, 256, 0, stream>>>(rep, x, indeg, tmp_incl, bsum,
                                                  norm_src, norm_dst, cbase16, xs);
    scan2_kernel<<<1, 256, 0, stream>>>(bsum, bofs, row_start);
    scanB_kernel<<<SCAN_BLOCKS, 256, 0, stream>>>(indeg, tmp_incl, bofs, row_start);
    fill2_kernel<<<128, 256, 0, stream>>>(src, dst, row_start, cbase16, edge_src);
    gather1_kernel<0><<<(N_NODES * 64) / 256, 256, 0, stream>>>(
        xs, edge_src, row_start, agg1);
    gather1_kernel<1><<<(N_NODES * 64) / 256, 256, 0, stream>>>(
        xs, edge_src, row_start, agg1);
    gemm_fused_kernel<<<(N_NODES + 63) / 64, 256, 0, stream>>>(
        agg1, W1, b1, W2, norm_dst, norm_src, h2);
    gather2_kernel<0><<<(N_NODES * 64) / 256, 256, 0, stream>>>(
        h2, edge_src, row_start, norm_dst, b2, out);
    gather2_kernel<1><<<(N_NODES * 64) / 256, 256, 0, stream>>>(
        h2, edge_src, row_start, norm_dst, b2, out);
}

// Round 9
// 166.279 us; speedup vs baseline: 1.2467x; 1.2467x over previous
//
#include <hip/hip_runtime.h>

#define N_NODES 50000
#define N_EDGES 800000
#define SCAN_BLOCKS ((N_NODES + 255) / 256)   // 196
#define CHUNKS 64
#define EDGES_PER_CHUNK (N_EDGES / CHUNKS)    // 12500
#define QUARTER_NODES 12500
#define WORDS_PER_QUARTER 6250                // u32 words (2 packed u16 counts each)
#define REP_WORDS 25000                       // u32 words per (arr,chunk) replica
// IN=64, HID=128, OUT=64

typedef unsigned short ushort_t;
typedef __attribute__((ext_vector_type(8))) short bf16x8;   // 8 bf16 (4 VGPRs)
typedef __attribute__((ext_vector_type(4))) float f32x4;

static __device__ __forceinline__ ushort_t f2bf(float f) {
    unsigned u = __float_as_uint(f);
    unsigned r = (u + 0x7fffu + ((u >> 16) & 1u)) >> 16;   // RNE
    return (ushort_t)r;
}
static __device__ __forceinline__ float bf2f(ushort_t u) {
    return __uint_as_float(((unsigned)u) << 16);
}

// Per-chunk privatized histogram over a quarter of the node range.
// 512 blocks = 2 arr x 4 quarter x 64 chunk, 25KB LDS each. No global atomics.
__global__ __launch_bounds__(256) void hist_kernel(const int* __restrict__ src,
                                                   const int* __restrict__ dst,
                                                   unsigned int* __restrict__ rep) {
    __shared__ unsigned int cnt[WORDS_PER_QUARTER];
    int bid = blockIdx.x;
    int chunk = bid & 63;
    int qf = (bid >> 6) & 3;
    int arr = bid >> 8;
    const int* ids = arr ? dst : src;
    int tid = threadIdx.x;
    for (int i = tid; i < WORDS_PER_QUARTER; i += 256) cnt[i] = 0;
    __syncthreads();
    int base = qf * QUARTER_NODES;
    int ebeg = chunk * EDGES_PER_CHUNK;
    for (int i = tid; i < EDGES_PER_CHUNK; i += 256) {
        int v = __builtin_nontemporal_load(&ids[ebeg + i]) - base;
        if ((unsigned)v < (unsigned)QUARTER_NODES)
            atomicAdd(&cnt[v >> 1], 1u << ((v & 1) << 4));  // LDS atomic, packed u16
    }
    __syncthreads();
    unsigned int* o = rep + ((size_t)arr * CHUNKS + chunk) * REP_WORDS + qf * WORDS_PER_QUARTER;
    for (int i = tid; i < WORDS_PER_QUARTER; i += 256) o[i] = cnt[i];
}

// Stage 1: reduce dst replicas -> indeg; per-block inclusive scan -> tmp_incl, bsum.
__global__ __launch_bounds__(256) void scan1_kernel(const unsigned int* __restrict__ rep,
                                                    int* __restrict__ indeg,
                                                    int* __restrict__ tmp_incl,
                                                    int* __restrict__ bsum) {
    __shared__ int lds[256];
    int tid = threadIdx.x;
    int i = blockIdx.x * 256 + tid;
    int v = 0;
    if (i < N_NODES) {
        int w = i >> 1, sh = (i & 1) << 4;
        const unsigned int* repd = rep + (size_t)CHUNKS * REP_WORDS;  // arr=1 (dst)
        #pragma unroll 8
        for (int c = 0; c < CHUNKS; c++)
            v += (int)((repd[(size_t)c * REP_WORDS + w] >> sh) & 0xffffu);
        indeg[i] = v;
    }
    lds[tid] = v;
    __syncthreads();
    for (int off = 1; off < 256; off <<= 1) {
        int t = (tid >= off) ? lds[tid - off] : 0;
        __syncthreads();
        lds[tid] += t;
        __syncthreads();
    }
    if (i < N_NODES) tmp_incl[i] = lds[tid];
    if (tid == 255) bsum[blockIdx.x] = lds[255];
}

// Stage 2: exclusive scan of block sums (1 block). Also writes row_start[N].
__global__ __launch_bounds__(256) void scan2_kernel(const int* __restrict__ bsum,
                                                    int* __restrict__ bofs,
                                                    int* __restrict__ row_start) {
    __shared__ int lds[256];
    int tid = threadIdx.x;
    lds[tid] = (tid < SCAN_BLOCKS) ? bsum[tid] : 0;
    __syncthreads();
    for (int off = 1; off < 256; off <<= 1) {
        int t = (tid >= off) ? lds[tid - off] : 0;
        __syncthreads();
        lds[tid] += t;
        __syncthreads();
    }
    if (tid < SCAN_BLOCKS) bofs[tid] = (tid == 0) ? 0 : lds[tid - 1];
    if (tid == SCAN_BLOCKS - 1) row_start[N_NODES] = lds[tid];
}

// Stage 3: row_start finalize + norms + absolute per-chunk cbase + fused
// xs = bf16(x * norm_src) prescale.
__global__ __launch_bounds__(256) void scan3_kernel(const unsigned int* __restrict__ rep,
                                                    const int* __restrict__ indeg,
                                                    const int* __restrict__ tmp_incl,
                                                    const int* __restrict__ bofs,
                                                    const float* __restrict__ x,
                                                    int* __restrict__ row_start,
                                                    float* __restrict__ norm_src,
                                                    float* __restrict__ norm_dst,
                                                    int* __restrict__ cbase,
                                                    ushort_t* __restrict__ xs) {
    int i = blockIdx.x * 256 + threadIdx.x;
    if (i >= N_NODES) return;
    int id = indeg[i];
    int rs = bofs[blockIdx.x] + tmp_incl[i] - id;
    row_start[i] = rs;
    int w = i >> 1, sh = (i & 1) << 4;
    int od = 0;
    #pragma unroll 8
    for (int c = 0; c < CHUNKS; c++)
        od += (int)((rep[(size_t)c * REP_WORDS + w] >> sh) & 0xffffu);  // arr=0 (src)
    float ns = 1.0f / sqrtf((float)max(od, 1));
    norm_src[i] = ns;
    norm_dst[i] = 1.0f / sqrtf((float)max(id, 1));
    const unsigned int* repd = rep + (size_t)CHUNKS * REP_WORDS;  // arr=1 (dst)
    int running = rs;
    for (int c = 0; c < CHUNKS; c++) {
        cbase[(size_t)c * N_NODES + i] = running;
        running += (int)((repd[(size_t)c * REP_WORDS + w] >> sh) & 0xffffu);
    }
    // fused prescale: xs row i = bf16(x row * ns)
    #pragma unroll
    for (int q = 0; q < 16; q++) {
        float4 v = *(const float4*)&x[(size_t)i * 64 + q * 4];
        ushort_t* o = &xs[(size_t)i * 64 + q * 4];
        o[0] = f2bf(v.x * ns); o[1] = f2bf(v.y * ns);
        o[2] = f2bf(v.z * ns); o[3] = f2bf(v.w * ns);
    }
}

// Counting-sort CSR fill, quarter-node blocks: 256 blocks = 4 quarter x 64
// chunk, 25KB LDS rank counters; pos = cbase[chunk][dst] + rank.
__global__ __launch_bounds__(256) void fill2_kernel(const int* __restrict__ src,
                                                    const int* __restrict__ dst,
                                                    const int* __restrict__ cbase,
                                                    int* __restrict__ edge_src) {
    __shared__ unsigned int rank[WORDS_PER_QUARTER];
    int chunk = blockIdx.x & 63;
    int qf = blockIdx.x >> 6;
    int tid = threadIdx.x;
    for (int i = tid; i < WORDS_PER_QUARTER; i += 256) rank[i] = 0;
    __syncthreads();
    int base = qf * QUARTER_NODES;
    int ebeg = chunk * EDGES_PER_CHUNK;
    for (int i = tid; i < EDGES_PER_CHUNK; i += 256) {
        int d = __builtin_nontemporal_load(&dst[ebeg + i]);
        int v = d - base;
        if ((unsigned)v < (unsigned)QUARTER_NODES) {
            int sh = (v & 1) << 4;
            unsigned old = atomicAdd(&rank[v >> 1], 1u << sh);
            int r = (int)((old >> sh) & 0xffffu);
            int pos = cbase[(size_t)chunk * N_NODES + d] + r;
            int sv = __builtin_nontemporal_load(&src[ebeg + i]);
            __builtin_nontemporal_store(sv, &edge_src[pos]);
        }
    }
}

// Quad-row gather: one wave per node; 4 lane-groups of 16 handle 4 edges per
// step, each group's 16 lanes load dwordx2 (4 bf16 cols) of its row -> 4 rows
// per load instruction, 16 rows in flight at unroll 4. bpermute broadcasts ids.
__global__ __launch_bounds__(256) void gather1_kernel(
        const ushort_t* __restrict__ xs, const int* __restrict__ edge_src,
        const int* __restrict__ row_start, float* __restrict__ agg) {
    int node = (blockIdx.x * blockDim.x + threadIdx.x) >> 6;
    int lane = threadIdx.x & 63;
    int grp = lane >> 4;        // edge sub-stream 0..3
    int lpos = lane & 15;       // column quad: cols 4*lpos..4*lpos+3
    int beg = row_start[node];
    int end = row_start[node + 1];
    float a0 = 0.f, a1 = 0.f, a2 = 0.f, a3 = 0.f;
    for (int i = beg; i < end; i += 64) {
        int cnt = min(end - i, 64);
        int ids = (lane < cnt) ? __builtin_nontemporal_load(&edge_src[i + lane]) : 0;
        for (int t = 0; t < cnt; t += 16) {
            #pragma unroll
            for (int q = 0; q < 4; q++) {
                int j = t + 4 * q + grp;
                int jj = max(min(j, cnt - 1), 0);
                int s = __builtin_amdgcn_ds_bpermute(jj << 2, ids);
                uint2 v = *(const uint2*)&xs[(size_t)s * 64 + lpos * 4];
                float m = (j < cnt) ? 1.f : 0.f;
                a0 = fmaf(__uint_as_float(v.x << 16), m, a0);
                a1 = fmaf(__uint_as_float(v.x & 0xffff0000u), m, a1);
                a2 = fmaf(__uint_as_float(v.y << 16), m, a2);
                a3 = fmaf(__uint_as_float(v.y & 0xffff0000u), m, a3);
            }
        }
    }
    a0 += __shfl_xor(a0, 16, 64); a1 += __shfl_xor(a1, 16, 64);
    a2 += __shfl_xor(a2, 16, 64); a3 += __shfl_xor(a3, 16, 64);
    a0 += __shfl_xor(a0, 32, 64); a1 += __shfl_xor(a1, 32, 64);
    a2 += __shfl_xor(a2, 32, 64); a3 += __shfl_xor(a3, 32, 64);
    if (grp == 0)
        *(float4*)&agg[(size_t)node * 64 + lpos * 4] = make_float4(a0, a1, a2, a3);
}

__global__ __launch_bounds__(256) void gather2_kernel(
        const ushort_t* __restrict__ h2, const int* __restrict__ edge_src,
        const int* __restrict__ row_start, const float* __restrict__ norm_dst,
        const float* __restrict__ b2, float* __restrict__ out) {
    int node = (blockIdx.x * blockDim.x + threadIdx.x) >> 6;
    int lane = threadIdx.x & 63;
    int grp = lane >> 4;
    int lpos = lane & 15;
    int beg = row_start[node];
    int end = row_start[node + 1];
    float a0 = 0.f, a1 = 0.f, a2 = 0.f, a3 = 0.f;
    for (int i = beg; i < end; i += 64) {
        int cnt = min(end - i, 64);
        int ids = (lane < cnt) ? __builtin_nontemporal_load(&edge_src[i + lane]) : 0;
        for (int t = 0; t < cnt; t += 16) {
            #pragma unroll
            for (int q = 0; q < 4; q++) {
                int j = t + 4 * q + grp;
                int jj = max(min(j, cnt - 1), 0);
                int s = __builtin_amdgcn_ds_bpermute(jj << 2, ids);
                uint2 v = *(const uint2*)&h2[(size_t)s * 64 + lpos * 4];
                float m = (j < cnt) ? 1.f : 0.f;
                a0 = fmaf(__uint_as_float(v.x << 16), m, a0);
                a1 = fmaf(__uint_as_float(v.x & 0xffff0000u), m, a1);
                a2 = fmaf(__uint_as_float(v.y << 16), m, a2);
                a3 = fmaf(__uint_as_float(v.y & 0xffff0000u), m, a3);
            }
        }
    }
    a0 += __shfl_xor(a0, 16, 64); a1 += __shfl_xor(a1, 16, 64);
    a2 += __shfl_xor(a2, 16, 64); a3 += __shfl_xor(a3, 16, 64);
    a0 += __shfl_xor(a0, 32, 64); a1 += __shfl_xor(a1, 32, 64);
    a2 += __shfl_xor(a2, 32, 64); a3 += __shfl_xor(a3, 32, 64);
    if (grp == 0) {
        float nd = norm_dst[node];
        float4 bb = *(const float4*)&b2[lpos * 4];
        *(float4*)&out[(size_t)node * 64 + lpos * 4] =
            make_float4(a0 * nd + bb.x, a1 * nd + bb.y, a2 * nd + bb.z, a3 * nd + bb.w);
    }
}

// MFMA fused MLP. Per block: 64 rows, 4 waves, each wave owns 16 rows.
// Layer1: [64x64]@[64x128] via hi/lo-split bf16 A (fp32-grade A). Layer2:
// [64x128]@[128x64] single bf16. Row padding (72/136 u16) spreads LDS banks.
__global__ __launch_bounds__(256) void gemm_fused_kernel(
        const float* __restrict__ agg, const float* __restrict__ W1,
        const float* __restrict__ b1, const float* __restrict__ W2,
        const float* __restrict__ norm_dst, const float* __restrict__ norm_src,
        ushort_t* __restrict__ h2) {
    __shared__ ushort_t mem[18432];   // 36 KB
    ushort_t* As_hi = mem;            // [64][72]
    ushort_t* As_lo = mem + 4608;     // [64][72]
    ushort_t* Wt1   = mem + 9216;     // [128 n][72 k]
    int tid = threadIdx.x;
    int rowbase = blockIdx.x * 64;

    for (int i = tid; i < 8192; i += 256) {
        int k = i >> 7, n = i & 127;
        Wt1[n * 72 + k] = f2bf(W1[i]);
    }
    for (int i = tid; i < 1024; i += 256) {
        int row = i >> 4;
        int c = (i & 15) * 4;
        int gr = rowbase + row;
        float4 v = make_float4(0.f, 0.f, 0.f, 0.f);
        if (gr < N_NODES) v = *(const float4*)&agg[(size_t)gr * 64 + c];
        float va[4] = {v.x, v.y, v.z, v.w};
        int base = row * 72 + c;
        #pragma unroll
        for (int q = 0; q < 4; q++) {
            ushort_t h = f2bf(va[q]);
            As_hi[base + q] = h;
            As_lo[base + q] = f2bf(va[q] - bf2f(h));
        }
    }
    __syncthreads();

    int lane = tid & 63;
    int w = tid >> 6;          // wave id 0..3 -> rows 16w..16w+15
    int lr = lane & 15;        // A-row / B-col within tile
    int hi8 = lane >> 4;       // k-group 0..3
    int a_off = (16 * w + lr) * 72 + hi8 * 8;

    f32x4 acc[8] = {};
    #pragma unroll
    for (int ks = 0; ks < 2; ks++) {
        bf16x8 ah = *(bf16x8*)&As_hi[a_off + ks * 32];
        bf16x8 al = *(bf16x8*)&As_lo[a_off + ks * 32];
        #pragma unroll
        for (int ct = 0; ct < 8; ct++) {
            bf16x8 b = *(bf16x8*)&Wt1[(ct * 16 + lr) * 72 + ks * 32 + hi8 * 8];
            acc[ct] = __builtin_amdgcn_mfma_f32_16x16x32_bf16(ah, b, acc[ct], 0, 0, 0);
            acc[ct] = __builtin_amdgcn_mfma_f32_16x16x32_bf16(al, b, acc[ct], 0, 0, 0);
        }
    }

    int row4 = hi8 * 4;
    float nd[4], ns[4];
    #pragma unroll
    for (int r = 0; r < 4; r++) {
        int gr = rowbase + 16 * w + row4 + r;
        nd[r] = (gr < N_NODES) ? norm_dst[gr] : 0.f;
        ns[r] = (gr < N_NODES) ? norm_src[gr] : 0.f;
    }
    __syncthreads();

    ushort_t* Hs  = mem;          // [64][136]
    ushort_t* Wt2 = mem + 8704;   // [64 n][136 k]
    for (int i = tid; i < 8192; i += 256) {
        int k = i >> 6, n = i & 63;
        Wt2[n * 136 + k] = f2bf(W2[i]);
    }
    #pragma unroll
    for (int ct = 0; ct < 8; ct++) {
        float bb = b1[ct * 16 + lr];
        #pragma unroll
        for (int r = 0; r < 4; r++) {
            float v = fmaxf(acc[ct][r] * nd[r] + bb, 0.f) * ns[r];
            Hs[(16 * w + row4 + r) * 136 + ct * 16 + lr] = f2bf(v);
        }
    }
    __syncthreads();

    f32x4 acc2[4] = {};
    int a2_off = (16 * w + lr) * 136 + hi8 * 8;
    #pragma unroll
    for (int ks = 0; ks < 4; ks++) {
        bf16x8 a2 = *(bf16x8*)&Hs[a2_off + ks * 32];
        #pragma unroll
        for (int ct = 0; ct < 4; ct++) {
            bf16x8 b = *(bf16x8*)&Wt2[(ct * 16 + lr) * 136 + ks * 32 + hi8 * 8];
            acc2[ct] = __builtin_amdgcn_mfma_f32_16x16x32_bf16(a2, b, acc2[ct], 0, 0, 0);
        }
    }
    #pragma unroll
    for (int ct = 0; ct < 4; ct++) {
        #pragma unroll
        for (int r = 0; r < 4; r++) {
            int gr = rowbase + 16 * w + row4 + r;
            if (gr < N_NODES)
                h2[(size_t)gr * 64 + ct * 16 + lr] = f2bf(acc2[ct][r]);
        }
    }
}

extern "C" void kernel_launch(void* const* d_in, const int* in_sizes, int n_in,
                              void* d_out, int out_size, void* d_ws, size_t ws_size,
                              hipStream_t stream) {
    const float* x  = (const float*)d_in[0];
    const float* W1 = (const float*)d_in[1];
    const float* b1 = (const float*)d_in[2];
    const float* W2 = (const float*)d_in[3];
    const float* b2 = (const float*)d_in[4];
    const int* src  = (const int*)d_in[5];
    const int* dst  = (const int*)d_in[6];
    float* out = (float*)d_out;

    int* indeg = (int*)d_ws;                        // N
    float* norm_src = (float*)(indeg + N_NODES);    // N
    float* norm_dst = norm_src + N_NODES;           // N
    int* row_start = (int*)(norm_dst + N_NODES);    // N+1
    int* tmp_incl = row_start + N_NODES + 1;        // N
    int* bsum = tmp_incl + N_NODES;                 // SCAN_BLOCKS
    int* bofs = bsum + SCAN_BLOCKS;                 // SCAN_BLOCKS
    unsigned int* rep = (unsigned int*)(bofs + SCAN_BLOCKS);      // 2*64*25000 u32
    int* edge_src = (int*)(rep + (size_t)2 * CHUNKS * REP_WORDS); // E
    int* cbase = edge_src + N_EDGES;                // 64*N ints
    float* agg1 = (float*)cbase;                    // N*64 f32 (aliases cbase; cbase dead after fill2)
    ushort_t* xs = (ushort_t*)(agg1 + (size_t)N_NODES * 64);  // N*64 bf16
    ushort_t* h2 = xs + (size_t)N_NODES * 64;                 // N*64 bf16

    hist_kernel<<<512, 256, 0, stream>>>(src, dst, rep);
    scan1_kernel<<<SCAN_BLOCKS, 256, 0, stream>>>(rep, indeg, tmp_incl, bsum);
    scan2_kernel<<<1, 256, 0, stream>>>(bsum, bofs, row_start);
    scan3_kernel<<<SCAN_BLOCKS, 256, 0, stream>>>(rep, indeg, tmp_incl, bofs, x,
                                                  row_start, norm_src, norm_dst,
                                                  cbase, xs);
    fill2_kernel<<<256, 256, 0, stream>>>(src, dst, cbase, edge_src);
    gather1_kernel<<<(N_NODES * 64) / 256, 256, 0, stream>>>(
        xs, edge_src, row_start, agg1);
    gemm_fused_kernel<<<(N_NODES + 63) / 64, 256, 0, stream>>>(
        agg1, W1, b1, W2, norm_dst, norm_src, h2);
    gather2_kernel<<<(N_NODES * 64) / 256, 256, 0, stream>>>(
        h2, edge_src, row_start, norm_dst, b2, out);
}

// Round 10
// 103.826 us; speedup vs baseline: 1.9966x; 1.6015x over previous
//
#include <hip/hip_runtime.h>

#define N_NODES 50000
#define N_EDGES 800000
#define SCAN_BLOCKS ((N_NODES + 255) / 256)   // 196
#define CHUNKS 64
#define EDGES_PER_CHUNK (N_EDGES / CHUNKS)    // 12500
#define QUARTER_NODES 12500
#define WORDS_PER_QUARTER 6250                // u32 words (2 packed u16 counts each)
#define REP_WORDS 25000                       // u32 words per (arr,chunk) replica
// IN=64, HID=128, OUT=64

typedef unsigned short ushort_t;
typedef __attribute__((ext_vector_type(8))) short bf16x8;   // 8 bf16 (4 VGPRs)
typedef __attribute__((ext_vector_type(4))) float f32x4;

static __device__ __forceinline__ ushort_t f2bf(float f) {
    unsigned u = __float_as_uint(f);
    unsigned r = (u + 0x7fffu + ((u >> 16) & 1u)) >> 16;   // RNE
    return (ushort_t)r;
}
static __device__ __forceinline__ float bf2f(ushort_t u) {
    return __uint_as_float(((unsigned)u) << 16);
}

// Per-chunk privatized histogram over a quarter of the node range.
// 512 blocks = 2 arr x 4 quarter x 64 chunk, 1024 thr, 25KB LDS each.
__global__ __launch_bounds__(1024) void hist_kernel(const int* __restrict__ src,
                                                    const int* __restrict__ dst,
                                                    unsigned int* __restrict__ rep) {
    __shared__ unsigned int cnt[WORDS_PER_QUARTER];
    int bid = blockIdx.x;
    int chunk = bid & 63;
    int qf = (bid >> 6) & 3;
    int arr = bid >> 8;
    const int* ids = arr ? dst : src;
    int tid = threadIdx.x;
    for (int i = tid; i < WORDS_PER_QUARTER; i += 1024) cnt[i] = 0;
    __syncthreads();
    int base = qf * QUARTER_NODES;
    int ebeg = chunk * EDGES_PER_CHUNK;
    for (int i = tid; i < EDGES_PER_CHUNK; i += 1024) {
        int v = ids[ebeg + i] - base;
        if ((unsigned)v < (unsigned)QUARTER_NODES)
            atomicAdd(&cnt[v >> 1], 1u << ((v & 1) << 4));  // LDS atomic, packed u16
    }
    __syncthreads();
    unsigned int* o = rep + ((size_t)arr * CHUNKS + chunk) * REP_WORDS + qf * WORDS_PER_QUARTER;
    for (int i = tid; i < WORDS_PER_QUARTER; i += 1024) o[i] = cnt[i];
}

// Stage 1: reduce dst replicas -> indeg; per-block inclusive scan -> tmp_incl, bsum.
__global__ __launch_bounds__(256) void scan1_kernel(const unsigned int* __restrict__ rep,
                                                    int* __restrict__ indeg,
                                                    int* __restrict__ tmp_incl,
                                                    int* __restrict__ bsum) {
    __shared__ int lds[256];
    int tid = threadIdx.x;
    int i = blockIdx.x * 256 + tid;
    int v = 0;
    if (i < N_NODES) {
        int w = i >> 1, sh = (i & 1) << 4;
        const unsigned int* repd = rep + (size_t)CHUNKS * REP_WORDS;  // arr=1 (dst)
        #pragma unroll 8
        for (int c = 0; c < CHUNKS; c++)
            v += (int)((repd[(size_t)c * REP_WORDS + w] >> sh) & 0xffffu);
        indeg[i] = v;
    }
    lds[tid] = v;
    __syncthreads();
    for (int off = 1; off < 256; off <<= 1) {
        int t = (tid >= off) ? lds[tid - off] : 0;
        __syncthreads();
        lds[tid] += t;
        __syncthreads();
    }
    if (i < N_NODES) tmp_incl[i] = lds[tid];
    if (tid == 255) bsum[blockIdx.x] = lds[255];
}

// Stage 2: exclusive scan of block sums (1 block). Also writes row_start[N].
__global__ __launch_bounds__(256) void scan2_kernel(const int* __restrict__ bsum,
                                                    int* __restrict__ bofs,
                                                    int* __restrict__ row_start) {
    __shared__ int lds[256];
    int tid = threadIdx.x;
    lds[tid] = (tid < SCAN_BLOCKS) ? bsum[tid] : 0;
    __syncthreads();
    for (int off = 1; off < 256; off <<= 1) {
        int t = (tid >= off) ? lds[tid - off] : 0;
        __syncthreads();
        lds[tid] += t;
        __syncthreads();
    }
    if (tid < SCAN_BLOCKS) bofs[tid] = (tid == 0) ? 0 : lds[tid - 1];
    if (tid == SCAN_BLOCKS - 1) row_start[N_NODES] = lds[tid];
}

// Stage 3: row_start finalize + norms + absolute per-chunk cbase + fused
// xs = bf16(x * norm_src) prescale.
__global__ __launch_bounds__(256) void scan3_kernel(const unsigned int* __restrict__ rep,
                                                    const int* __restrict__ indeg,
                                                    const int* __restrict__ tmp_incl,
                                                    const int* __restrict__ bofs,
                                                    const float* __restrict__ x,
                                                    int* __restrict__ row_start,
                                                    float* __restrict__ norm_src,
                                                    float* __restrict__ norm_dst,
                                                    int* __restrict__ cbase,
                                                    ushort_t* __restrict__ xs) {
    int i = blockIdx.x * 256 + threadIdx.x;
    if (i >= N_NODES) return;
    int id = indeg[i];
    int rs = bofs[blockIdx.x] + tmp_incl[i] - id;
    row_start[i] = rs;
    int w = i >> 1, sh = (i & 1) << 4;
    int od = 0;
    #pragma unroll 8
    for (int c = 0; c < CHUNKS; c++)
        od += (int)((rep[(size_t)c * REP_WORDS + w] >> sh) & 0xffffu);  // arr=0 (src)
    float ns = 1.0f / sqrtf((float)max(od, 1));
    norm_src[i] = ns;
    norm_dst[i] = 1.0f / sqrtf((float)max(id, 1));
    const unsigned int* repd = rep + (size_t)CHUNKS * REP_WORDS;  // arr=1 (dst)
    int running = rs;
    for (int c = 0; c < CHUNKS; c++) {
        cbase[(size_t)c * N_NODES + i] = running;
        running += (int)((repd[(size_t)c * REP_WORDS + w] >> sh) & 0xffffu);
    }
    // fused prescale: xs row i = bf16(x row * ns)
    #pragma unroll
    for (int q = 0; q < 16; q++) {
        float4 v = *(const float4*)&x[(size_t)i * 64 + q * 4];
        ushort_t* o = &xs[(size_t)i * 64 + q * 4];
        o[0] = f2bf(v.x * ns); o[1] = f2bf(v.y * ns);
        o[2] = f2bf(v.z * ns); o[3] = f2bf(v.w * ns);
    }
}

// Counting-sort CSR fill, quarter-node blocks: 256 blocks = 4 quarter x 64
// chunk, 1024 thr (16 waves/CU to hide cbase latency), 25KB LDS rank
// counters; pos = cbase[chunk][dst] + rank. Plain stores: L2 write-back
// absorbs the 4B scatter (edge_src is 3.2MB, L2-resident).
__global__ __launch_bounds__(1024) void fill2_kernel(const int* __restrict__ src,
                                                     const int* __restrict__ dst,
                                                     const int* __restrict__ cbase,
                                                     int* __restrict__ edge_src) {
    __shared__ unsigned int rank[WORDS_PER_QUARTER];
    int chunk = blockIdx.x & 63;
    int qf = blockIdx.x >> 6;
    int tid = threadIdx.x;
    for (int i = tid; i < WORDS_PER_QUARTER; i += 1024) rank[i] = 0;
    __syncthreads();
    int base = qf * QUARTER_NODES;
    int ebeg = chunk * EDGES_PER_CHUNK;
    for (int i = tid; i < EDGES_PER_CHUNK; i += 1024) {
        int d = dst[ebeg + i];
        int v = d - base;
        if ((unsigned)v < (unsigned)QUARTER_NODES) {
            int sh = (v & 1) << 4;
            unsigned old = atomicAdd(&rank[v >> 1], 1u << sh);
            int r = (int)((old >> sh) & 0xffffu);
            int pos = cbase[(size_t)chunk * N_NODES + d] + r;
            edge_src[pos] = src[ebeg + i];
        }
    }
}

// Quad-row gather: one wave per node; 4 lane-groups of 16 handle 4 edges per
// step, each group's 16 lanes load dwordx2 (4 bf16 cols) of its row -> 4 rows
// per load instruction, 16 rows in flight at unroll 4. bpermute broadcasts ids.
__global__ __launch_bounds__(256) void gather1_kernel(
        const ushort_t* __restrict__ xs, const int* __restrict__ edge_src,
        const int* __restrict__ row_start, float* __restrict__ agg) {
    int node = (blockIdx.x * blockDim.x + threadIdx.x) >> 6;
    int lane = threadIdx.x & 63;
    int grp = lane >> 4;        // edge sub-stream 0..3
    int lpos = lane & 15;       // column quad: cols 4*lpos..4*lpos+3
    int beg = row_start[node];
    int end = row_start[node + 1];
    float a0 = 0.f, a1 = 0.f, a2 = 0.f, a3 = 0.f;
    for (int i = beg; i < end; i += 64) {
        int cnt = min(end - i, 64);
        int ids = (lane < cnt) ? edge_src[i + lane] : 0;
        for (int t = 0; t < cnt; t += 16) {
            #pragma unroll
            for (int q = 0; q < 4; q++) {
                int j = t + 4 * q + grp;
                int jj = max(min(j, cnt - 1), 0);
                int s = __builtin_amdgcn_ds_bpermute(jj << 2, ids);
                uint2 v = *(const uint2*)&xs[(size_t)s * 64 + lpos * 4];
                float m = (j < cnt) ? 1.f : 0.f;
                a0 = fmaf(__uint_as_float(v.x << 16), m, a0);
                a1 = fmaf(__uint_as_float(v.x & 0xffff0000u), m, a1);
                a2 = fmaf(__uint_as_float(v.y << 16), m, a2);
                a3 = fmaf(__uint_as_float(v.y & 0xffff0000u), m, a3);
            }
        }
    }
    a0 += __shfl_xor(a0, 16, 64); a1 += __shfl_xor(a1, 16, 64);
    a2 += __shfl_xor(a2, 16, 64); a3 += __shfl_xor(a3, 16, 64);
    a0 += __shfl_xor(a0, 32, 64); a1 += __shfl_xor(a1, 32, 64);
    a2 += __shfl_xor(a2, 32, 64); a3 += __shfl_xor(a3, 32, 64);
    if (grp == 0)
        *(float4*)&agg[(size_t)node * 64 + lpos * 4] = make_float4(a0, a1, a2, a3);
}

__global__ __launch_bounds__(256) void gather2_kernel(
        const ushort_t* __restrict__ h2, const int* __restrict__ edge_src,
        const int* __restrict__ row_start, const float* __restrict__ norm_dst,
        const float* __restrict__ b2, float* __restrict__ out) {
    int node = (blockIdx.x * blockDim.x + threadIdx.x) >> 6;
    int lane = threadIdx.x & 63;
    int grp = lane >> 4;
    int lpos = lane & 15;
    int beg = row_start[node];
    int end = row_start[node + 1];
    float a0 = 0.f, a1 = 0.f, a2 = 0.f, a3 = 0.f;
    for (int i = beg; i < end; i += 64) {
        int cnt = min(end - i, 64);
        int ids = (lane < cnt) ? edge_src[i + lane] : 0;
        for (int t = 0; t < cnt; t += 16) {
            #pragma unroll
            for (int q = 0; q < 4; q++) {
                int j = t + 4 * q + grp;
                int jj = max(min(j, cnt - 1), 0);
                int s = __builtin_amdgcn_ds_bpermute(jj << 2, ids);
                uint2 v = *(const uint2*)&h2[(size_t)s * 64 + lpos * 4];
                float m = (j < cnt) ? 1.f : 0.f;
                a0 = fmaf(__uint_as_float(v.x << 16), m, a0);
                a1 = fmaf(__uint_as_float(v.x & 0xffff0000u), m, a1);
                a2 = fmaf(__uint_as_float(v.y << 16), m, a2);
                a3 = fmaf(__uint_as_float(v.y & 0xffff0000u), m, a3);
            }
        }
    }
    a0 += __shfl_xor(a0, 16, 64); a1 += __shfl_xor(a1, 16, 64);
    a2 += __shfl_xor(a2, 16, 64); a3 += __shfl_xor(a3, 16, 64);
    a0 += __shfl_xor(a0, 32, 64); a1 += __shfl_xor(a1, 32, 64);
    a2 += __shfl_xor(a2, 32, 64); a3 += __shfl_xor(a3, 32, 64);
    if (grp == 0) {
        float nd = norm_dst[node];
        float4 bb = *(const float4*)&b2[lpos * 4];
        *(float4*)&out[(size_t)node * 64 + lpos * 4] =
            make_float4(a0 * nd + bb.x, a1 * nd + bb.y, a2 * nd + bb.z, a3 * nd + bb.w);
    }
}

// MFMA fused MLP. Per block: 64 rows, 4 waves, each wave owns 16 rows.
// Layer1: [64x64]@[64x128] via hi/lo-split bf16 A (fp32-grade A). Layer2:
// [64x128]@[128x64] single bf16. Row padding (72/136 u16) spreads LDS banks.
__global__ __launch_bounds__(256) void gemm_fused_kernel(
        const float* __restrict__ agg, const float* __restrict__ W1,
        const float* __restrict__ b1, const float* __restrict__ W2,
        const float* __restrict__ norm_dst, const float* __restrict__ norm_src,
        ushort_t* __restrict__ h2) {
    __shared__ ushort_t mem[18432];   // 36 KB
    ushort_t* As_hi = mem;            // [64][72]
    ushort_t* As_lo = mem + 4608;     // [64][72]
    ushort_t* Wt1   = mem + 9216;     // [128 n][72 k]
    int tid = threadIdx.x;
    int rowbase = blockIdx.x * 64;

    for (int i = tid; i < 8192; i += 256) {
        int k = i >> 7, n = i & 127;
        Wt1[n * 72 + k] = f2bf(W1[i]);
    }
    for (int i = tid; i < 1024; i += 256) {
        int row = i >> 4;
        int c = (i & 15) * 4;
        int gr = rowbase + row;
        float4 v = make_float4(0.f, 0.f, 0.f, 0.f);
        if (gr < N_NODES) v = *(const float4*)&agg[(size_t)gr * 64 + c];
        float va[4] = {v.x, v.y, v.z, v.w};
        int base = row * 72 + c;
        #pragma unroll
        for (int q = 0; q < 4; q++) {
            ushort_t h = f2bf(va[q]);
            As_hi[base + q] = h;
            As_lo[base + q] = f2bf(va[q] - bf2f(h));
        }
    }
    __syncthreads();

    int lane = tid & 63;
    int w = tid >> 6;          // wave id 0..3 -> rows 16w..16w+15
    int lr = lane & 15;        // A-row / B-col within tile
    int hi8 = lane >> 4;       // k-group 0..3
    int a_off = (16 * w + lr) * 72 + hi8 * 8;

    f32x4 acc[8] = {};
    #pragma unroll
    for (int ks = 0; ks < 2; ks++) {
        bf16x8 ah = *(bf16x8*)&As_hi[a_off + ks * 32];
        bf16x8 al = *(bf16x8*)&As_lo[a_off + ks * 32];
        #pragma unroll
        for (int ct = 0; ct < 8; ct++) {
            bf16x8 b = *(bf16x8*)&Wt1[(ct * 16 + lr) * 72 + ks * 32 + hi8 * 8];
            acc[ct] = __builtin_amdgcn_mfma_f32_16x16x32_bf16(ah, b, acc[ct], 0, 0, 0);
            acc[ct] = __builtin_amdgcn_mfma_f32_16x16x32_bf16(al, b, acc[ct], 0, 0, 0);
        }
    }

    int row4 = hi8 * 4;
    float nd[4], ns[4];
    #pragma unroll
    for (int r = 0; r < 4; r++) {
        int gr = rowbase + 16 * w + row4 + r;
        nd[r] = (gr < N_NODES) ? norm_dst[gr] : 0.f;
        ns[r] = (gr < N_NODES) ? norm_src[gr] : 0.f;
    }
    __syncthreads();

    ushort_t* Hs  = mem;          // [64][136]
    ushort_t* Wt2 = mem + 8704;   // [64 n][136 k]
    for (int i = tid; i < 8192; i += 256) {
        int k = i >> 6, n = i & 63;
        Wt2[n * 136 + k] = f2bf(W2[i]);
    }
    #pragma unroll
    for (int ct = 0; ct < 8; ct++) {
        float bb = b1[ct * 16 + lr];
        #pragma unroll
        for (int r = 0; r < 4; r++) {
            float v = fmaxf(acc[ct][r] * nd[r] + bb, 0.f) * ns[r];
            Hs[(16 * w + row4 + r) * 136 + ct * 16 + lr] = f2bf(v);
        }
    }
    __syncthreads();

    f32x4 acc2[4] = {};
    int a2_off = (16 * w + lr) * 136 + hi8 * 8;
    #pragma unroll
    for (int ks = 0; ks < 4; ks++) {
        bf16x8 a2 = *(bf16x8*)&Hs[a2_off + ks * 32];
        #pragma unroll
        for (int ct = 0; ct < 4; ct++) {
            bf16x8 b = *(bf16x8*)&Wt2[(ct * 16 + lr) * 136 + ks * 32 + hi8 * 8];
            acc2[ct] = __builtin_amdgcn_mfma_f32_16x16x32_bf16(a2, b, acc2[ct], 0, 0, 0);
        }
    }
    #pragma unroll
    for (int ct = 0; ct < 4; ct++) {
        #pragma unroll
        for (int r = 0; r < 4; r++) {
            int gr = rowbase + 16 * w + row4 + r;
            if (gr < N_NODES)
                h2[(size_t)gr * 64 + ct * 16 + lr] = f2bf(acc2[ct][r]);
        }
    }
}

extern "C" void kernel_launch(void* const* d_in, const int* in_sizes, int n_in,
                              void* d_out, int out_size, void* d_ws, size_t ws_size,
                              hipStream_t stream) {
    const float* x  = (const float*)d_in[0];
    const float* W1 = (const float*)d_in[1];
    const float* b1 = (const float*)d_in[2];
    const float* W2 = (const float*)d_in[3];
    const float* b2 = (const float*)d_in[4];
    const int* src  = (const int*)d_in[5];
    const int* dst  = (const int*)d_in[6];
    float* out = (float*)d_out;

    int* indeg = (int*)d_ws;                        // N
    float* norm_src = (float*)(indeg + N_NODES);    // N
    float* norm_dst = norm_src + N_NODES;           // N
    int* row_start = (int*)(norm_dst + N_NODES);    // N+1
    int* tmp_incl = row_start + N_NODES + 1;        // N
    int* bsum = tmp_incl + N_NODES;                 // SCAN_BLOCKS
    int* bofs = bsum + SCAN_BLOCKS;                 // SCAN_BLOCKS
    unsigned int* rep = (unsigned int*)(bofs + SCAN_BLOCKS);      // 2*64*25000 u32
    int* edge_src = (int*)(rep + (size_t)2 * CHUNKS * REP_WORDS); // E
    int* cbase = edge_src + N_EDGES;                // 64*N ints
    float* agg1 = (float*)cbase;                    // N*64 f32 (aliases cbase; cbase dead after fill2)
    ushort_t* xs = (ushort_t*)(agg1 + (size_t)N_NODES * 64);  // N*64 bf16
    ushort_t* h2 = xs + (size_t)N_NODES * 64;                 // N*64 bf16

    hist_kernel<<<512, 1024, 0, stream>>>(src, dst, rep);
    scan1_kernel<<<SCAN_BLOCKS, 256, 0, stream>>>(rep, indeg, tmp_incl, bsum);
    scan2_kernel<<<1, 256, 0, stream>>>(bsum, bofs, row_start);
    scan3_kernel<<<SCAN_BLOCKS, 256, 0, stream>>>(rep, indeg, tmp_incl, bofs, x,
                                                  row_start, norm_src, norm_dst,
                                                  cbase, xs);
    fill2_kernel<<<256, 1024, 0, stream>>>(src, dst, cbase, edge_src);
    gather1_kernel<<<(N_NODES * 64) / 256, 256, 0, stream>>>(
        xs, edge_src, row_start, agg1);
    gemm_fused_kernel<<<(N_NODES + 63) / 64, 256, 0, stream>>>(
        agg1, W1, b1, W2, norm_dst, norm_src, h2);
    gather2_kernel<<<(N_NODES * 64) / 256, 256, 0, stream>>>(
        h2, edge_src, row_start, norm_dst, b2, out);
}